// Round 6
// baseline (460.792 us; speedup 1.0000x reference)
//
#include <hip/hip_runtime.h>
#include <hip/hip_bf16.h>

#define DEV __device__ __forceinline__

typedef __bf16 bf16x8 __attribute__((ext_vector_type(8)));
typedef __bf16 bf16x4 __attribute__((ext_vector_type(4)));
typedef float f32x4 __attribute__((ext_vector_type(4)));

static constexpr int kB = 2, kT = 2048, kD = 2048, kH = 16, kHD = 128;
static constexpr int kBT = kB * kT;  // 4096

#if __has_builtin(__builtin_amdgcn_exp2f)
DEV float fast_exp2(float x) { return __builtin_amdgcn_exp2f(x); }
#else
DEV float fast_exp2(float x) { return exp2f(x); }
#endif

DEV unsigned short f2bf(float f) {
  union { __hip_bfloat16 h; unsigned short u; } cv;
  cv.h = __float2bfloat16(f);
  return cv.u;
}

// async global->LDS, 16B per lane. LDS dest must be wave-uniform base + lane*16.
DEV void gl_lds16(const void* g, void* l) {
  __builtin_amdgcn_global_load_lds(
      (const __attribute__((address_space(1))) unsigned int*)g,
      (__attribute__((address_space(3))) unsigned int*)l, 16, 0, 0);
}

#define MFMA(a, b, c) __builtin_amdgcn_mfma_f32_16x16x32_bf16(a, b, c, 0, 0, 0)

// chunk swizzle for 128x64 bf16 tiles (8 chunks/row): frag-read lanes spread
// over all 8 4-bank spans (b128 floor). swz8 over 16 consecutive rows = 0..7 x2.
DEV int swz8(int row) { return (row ^ (row >> 3)) & 7; }

// ---------------- fp32 -> bf16 conversion of the 3 weight matrices ----------
__global__ __launch_bounds__(256) void cvt3_kernel(
    const float* __restrict__ s0, const float* __restrict__ s1,
    const float* __restrict__ s2, unsigned short* __restrict__ d0,
    unsigned short* __restrict__ d1, unsigned short* __restrict__ d2, int n4) {
  const int y = blockIdx.y;
  const float* s = y == 0 ? s0 : y == 1 ? s1 : s2;
  unsigned short* d = y == 0 ? d0 : y == 1 ? d1 : d2;
  int i = blockIdx.x * 256 + threadIdx.x;
  if (i >= n4) return;
  float4 v = ((const float4*)s)[i];
  ushort4 o;
  o.x = f2bf(v.x); o.y = f2bf(v.y); o.z = f2bf(v.z); o.w = f2bf(v.w);
  ((ushort4*)d)[i] = o;
}

// ---- make_vt + x-cvt fused: reads x once, emits xb (bf16) and V^T -----
// top_k with TOPK==NVK==4 selects ALL rows -> c[d] = 2*sum_{k<4} v_embed[k][d].
// Thread holds an 8t x 4d register block: xb written directly (coalesced);
// V^T transposed through 16B-chunk-swizzled LDS (b128 writes+reads, ~floor
// banks) then written coalesced to [b][h][hd][T].
__global__ __launch_bounds__(256) void make_vt_kernel(
    const float* __restrict__ x, const float* __restrict__ v_embed,
    unsigned short* __restrict__ vt, unsigned short* __restrict__ xb) {
  __shared__ __align__(16) unsigned short sT[128 * 64];  // [hd][chunk(t/8)][8]
  const int t0 = blockIdx.x * 64, h = blockIdx.y, b = blockIdx.z;
  const int tid = threadIdx.x;
  const int d4 = tid & 31, tw = tid >> 5;  // tw 0..7
  const int dg = h * kHD + d4 * 4;
  float4 e0 = *(const float4*)(v_embed + dg);
  float4 e1 = *(const float4*)(v_embed + kD + dg);
  float4 e2 = *(const float4*)(v_embed + 2 * kD + dg);
  float4 e3 = *(const float4*)(v_embed + 3 * kD + dg);
  float c4[4];
  c4[0] = 2.f * (e0.x + e1.x + e2.x + e3.x);
  c4[1] = 2.f * (e0.y + e1.y + e2.y + e3.y);
  c4[2] = 2.f * (e0.z + e1.z + e2.z + e3.z);
  c4[3] = 2.f * (e0.w + e1.w + e2.w + e3.w);
  float4 v[8];
#pragma unroll
  for (int j = 0; j < 8; j++)
    v[j] = *(const float4*)(x + (size_t)(b * kT + t0 + tw * 8 + j) * kD + dg);
  // xb: plain bf16 copy of x (coalesced 8B/lane)
#pragma unroll
  for (int j = 0; j < 8; j++) {
    ushort4 o;
    o.x = f2bf(v[j].x); o.y = f2bf(v[j].y); o.z = f2bf(v[j].z); o.w = f2bf(v[j].w);
    *(ushort4*)(xb + (size_t)(b * kT + t0 + tw * 8 + j) * kD + dg) = o;
  }
  // scaled transpose into LDS: row hd, chunk tw ^ (hd&7)
#pragma unroll
  for (int c = 0; c < 4; c++) {
    const int hd = d4 * 4 + c;
    union { bf16x8 v8; unsigned short u[8]; } w8;
#pragma unroll
    for (int j = 0; j < 8; j++)
      w8.u[j] = f2bf(((const float*)&v[j])[c] * c4[c]);
    *(bf16x8*)(&sT[hd * 64 + (tw ^ (hd & 7)) * 8]) = w8.v8;
  }
  __syncthreads();
#pragma unroll
  for (int it = 0; it < 4; it++) {
    const int hd = (tid >> 3) + it * 32;
    const int rc = tid & 7;
    bf16x8 vv = *(const bf16x8*)(&sT[hd * 64 + (rc ^ (hd & 7)) * 8]);
    *(bf16x8*)(vt + ((size_t)((b * kH + h) * kHD + hd)) * kT + t0 + rc * 8) = vv;
  }
}

// ---------------- C[m,n] = (sum_k A[m,k]*B[n,k] + bias[n]) * scale ----------
// 128x128 tile, BK=64 (32 iters, half the barriers), 4 waves (2x2), 16x16x32
// MFMA, global_load_lds w=16, swz8 chunk swizzle (frag reads at b128 floor).
template <bool BF16OUT, bool FUSED2>
__global__ __launch_bounds__(256, 4) void gemm_bt(
    const unsigned short* __restrict__ A, const unsigned short* __restrict__ B1,
    const unsigned short* __restrict__ B2, const float* __restrict__ bias1,
    const float* __restrict__ bias2, void* __restrict__ C1, void* __restrict__ C2,
    float scale1, float scale2) {
  constexpr int N = kD, K = kD;
  __shared__ __align__(16) unsigned short As[128 * 64], Bs[128 * 64];
  const unsigned short* Bm = (FUSED2 && blockIdx.z) ? B2 : B1;
  const float* bias = (FUSED2 && blockIdx.z) ? bias2 : bias1;
  void* Cout = (FUSED2 && blockIdx.z) ? C2 : C1;
  const float scale = (FUSED2 && blockIdx.z) ? scale2 : scale1;
  const int tid = threadIdx.x;
  const int lane = tid & 63, wave = tid >> 6;
  const int wr = wave >> 1, wc = wave & 1;
  const int m0 = blockIdx.y * 128, n0 = blockIdx.x * 128;
  const int frow = lane & 15, fc = lane >> 4;

  f32x4 acc[4][4];
  for (int i = 0; i < 4; i++)
    for (int j = 0; j < 4; j++)
      for (int r = 0; r < 4; r++) acc[i][j][r] = 0.f;

  const unsigned short* Ab = A + (size_t)m0 * K;
  const unsigned short* Bb = Bm + (size_t)n0 * K;

  for (int k0 = 0; k0 < K; k0 += 64) {
    __syncthreads();
#pragma unroll
    for (int i = 0; i < 8; i++) {
      const int idx = tid + i * 256;
      const int row = idx >> 3, dc = (idx & 7) ^ swz8(row);
      gl_lds16(Ab + (size_t)row * K + k0 + dc * 8, As + idx * 8);
    }
#pragma unroll
    for (int i = 0; i < 8; i++) {
      const int idx = tid + i * 256;
      const int row = idx >> 3, dc = (idx & 7) ^ swz8(row);
      gl_lds16(Bb + (size_t)row * K + k0 + dc * 8, Bs + idx * 8);
    }
    __syncthreads();
#pragma unroll
    for (int ks = 0; ks < 2; ks++) {
      bf16x8 af[4], bfr[4];
#pragma unroll
      for (int mi = 0; mi < 4; mi++) {
        const int row = wr * 64 + mi * 16 + frow;
        af[mi] = *(const bf16x8*)(As + (row * 8 + ((ks * 4 + fc) ^ swz8(row))) * 8);
      }
#pragma unroll
      for (int ni = 0; ni < 4; ni++) {
        const int row = wc * 64 + ni * 16 + frow;
        bfr[ni] = *(const bf16x8*)(Bs + (row * 8 + ((ks * 4 + fc) ^ swz8(row))) * 8);
      }
#pragma unroll
      for (int mi = 0; mi < 4; mi++)
#pragma unroll
        for (int ni = 0; ni < 4; ni++)
          acc[mi][ni] = MFMA(af[mi], bfr[ni], acc[mi][ni]);
    }
  }
  // epilogue: C/D layout col=lane&15, row=(lane>>4)*4+reg
  for (int ni = 0; ni < 4; ni++) {
    const int n = n0 + wc * 64 + ni * 16 + frow;
    const float bs = bias[n];
    for (int mi = 0; mi < 4; mi++) {
      const int mb = m0 + wr * 64 + mi * 16 + fc * 4;
      for (int r = 0; r < 4; r++) {
        const float v = (acc[mi][ni][r] + bs) * scale;
        if (BF16OUT)
          ((unsigned short*)Cout)[(size_t)(mb + r) * N + n] = f2bf(v);
        else
          ((float*)Cout)[(size_t)(mb + r) * N + n] = v;
      }
    }
  }
}

// K/V tile staging: 64 keys x 128 hd each, 16B-chunk swizzled.
DEV void stage_kv(const unsigned short* __restrict__ Kg,
                  const unsigned short* __restrict__ Vt, unsigned short* dK,
                  unsigned short* dV, int tid, int b, int h, int k0) {
#pragma unroll
  for (int i = 0; i < 4; i++) {
    const int idx = tid + i * 256;
    const int key = idx >> 4, cc = (idx & 15) ^ (key & 15);
    gl_lds16(Kg + (size_t)(b * kT + k0 + key) * kD + h * kHD + cc * 8, dK + idx * 8);
  }
#pragma unroll
  for (int i = 0; i < 4; i++) {
    const int idx = tid + i * 256;
    const int hd = idx >> 3;
    const int cc = (idx & 7) ^ (hd & 7) ^ (((hd >> 3) & 1) << 2);
    gl_lds16(Vt + ((size_t)((b * kH + h) * kHD + hd)) * kT + k0 + cc * 8, dV + idx * 8);
  }
}

// ---------------- flash attention v3, causal, S^T formulation ----------------
// Q PRE-SCALED by (1/sqrt(HD))*log2(e); exp2-domain softmax. 128-row q-tile per
// block; each wave owns 32 q-columns (2 fragment groups) so every K/V LDS read
// feeds 2 MFMAs (halves LDS-read traffic vs R5). Grid 512 (all co-resident at
// 2 blocks/CU); adjacent bids pair qt=(15-j, j) -> per-CU load ~constant.
// PV via slot remap onto the K=32 MFMA (R4 notes).
__global__ __launch_bounds__(256, 2) void attn3_kernel(
    const unsigned short* __restrict__ Q, const unsigned short* __restrict__ Kg,
    const unsigned short* __restrict__ Vt, unsigned short* __restrict__ O) {
  __shared__ __align__(16) unsigned short sK[2][64 * 128];  // [key][hd]
  __shared__ __align__(16) unsigned short sV[2][64 * 128];  // [hd][key]
  const int tid = threadIdx.x, l = tid & 63, w = tid >> 6;
  const int g = l >> 4, q15 = l & 15;
  const int bid = blockIdx.x;
  const int pair = bid >> 1, j = pair >> 5;       // j 0..7
  const int qt = (bid & 1) ? j : (15 - j);        // heavy/light interleave
  const int gidx = pair & 31;
  const int h = gidx & 15, b = gidx >> 4;
  const int q0 = qt * 128;
  const int nkb = 2 * qt + 2;
  const int qA = q0 + w * 32 + q15;  // group 0 q; group 1 = qA+16

  stage_kv(Kg, Vt, &sK[0][0], &sV[0][0], tid, b, h, 0);

  bf16x8 qf[2][4];
#pragma unroll
  for (int g2 = 0; g2 < 2; g2++) {
    const unsigned short* Qrow = Q + (size_t)(b * kT + qA + 16 * g2) * kD + h * kHD;
#pragma unroll
    for (int kk = 0; kk < 4; kk++)
      qf[g2][kk] = *(const bf16x8*)(Qrow + kk * 32 + g * 8);
  }

  f32x4 oacc[2][8];
#pragma unroll
  for (int g2 = 0; g2 < 2; g2++)
    for (int ni = 0; ni < 8; ni++)
      for (int r = 0; r < 4; r++) oacc[g2][ni][r] = 0.f;
  float m_i[2] = {-1e30f, -1e30f}, l_i[2] = {0.f, 0.f};

  for (int kb = 0; kb < nkb; kb++) {
    const int bb = kb & 1;
    __syncthreads();  // drains prefetch(kb), syncs buffers
    if (kb + 1 < nkb)
      stage_kv(Kg, Vt, &sK[1 - bb][0], &sV[1 - bb][0], tid, b, h, (kb + 1) * 64);

    // S^T = K Q^T : lane holds S^T[key = s*16 + 4g + r][q(g2)]
    f32x4 st[2][4];
#pragma unroll
    for (int g2 = 0; g2 < 2; g2++)
      for (int s = 0; s < 4; s++)
        for (int r = 0; r < 4; r++) st[g2][s][r] = 0.f;
#pragma unroll
    for (int s = 0; s < 4; s++) {
      const int key = s * 16 + q15;  // A-frag row for this lane
#pragma unroll
      for (int kk = 0; kk < 4; kk++) {
        bf16x8 kf = *(const bf16x8*)(
            &sK[bb][(key * 16 + ((kk * 4 + g) ^ (key & 15))) * 8]);
        st[0][s] = MFMA(kf, qf[0][kk], st[0][s]);
        st[1][s] = MFMA(kf, qf[1][kk], st[1][s]);
      }
    }
    // causal mask (last two units hold the diagonal)
    if (kb >= nkb - 2) {
      const int kbase = kb * 64;
#pragma unroll
      for (int g2 = 0; g2 < 2; g2++)
        for (int s = 0; s < 4; s++)
          for (int r = 0; r < 4; r++)
            if (kbase + s * 16 + g * 4 + r > qA + 16 * g2) st[g2][s][r] = -1e30f;
    }
    // online softmax per group (exp2 domain), stats in-register + 2 shfl
    union { bf16x8 v; unsigned short u[8]; } pkv[2][2];
#pragma unroll
    for (int g2 = 0; g2 < 2; g2++) {
      float mx = -1e30f;
#pragma unroll
      for (int s = 0; s < 4; s++)
        for (int r = 0; r < 4; r++) mx = fmaxf(mx, st[g2][s][r]);
      mx = fmaxf(mx, __shfl_xor(mx, 16, 64));
      mx = fmaxf(mx, __shfl_xor(mx, 32, 64));
      const float mn = fmaxf(m_i[g2], mx);
      const float alpha = fast_exp2(m_i[g2] - mn);
      float rs = 0.f;
#pragma unroll
      for (int s = 0; s < 4; s++)
        for (int r = 0; r < 4; r++) {
          const float p = fast_exp2(st[g2][s][r] - mn);
          rs += p;
          pkv[g2][s >> 1].u[(s & 1) * 4 + r] = f2bf(p);  // slot j=(s&1)*4+r
        }
      rs += __shfl_xor(rs, 16, 64);
      rs += __shfl_xor(rs, 32, 64);
      m_i[g2] = mn;
      l_i[g2] = l_i[g2] * alpha + rs;
#pragma unroll
      for (int ni = 0; ni < 8; ni++)
        for (int r = 0; r < 4; r++) oacc[g2][ni][r] *= alpha;
    }
    // O^T += V^T P^T; A-frag slot (g,j) = key 32c+(j>>2)*16+4g+(j&3); V read
    // once, used by both groups.
#pragma unroll
    for (int ni = 0; ni < 8; ni++) {
      const int hd = ni * 16 + q15;
      const int hx = (hd & 7) ^ (((hd >> 3) & 1) << 2), base = hd * 8;
#pragma unroll
      for (int c = 0; c < 2; c++) {
        const int c4l = 8 * c + g;       // keys 32c+4g+0..3   (j=0..3)
        const int c4h = 8 * c + 4 + g;   // keys 32c+16+4g+0..3 (j=4..7)
        bf16x4 lo = *(const bf16x4*)(
            &sV[bb][(base + ((c4l >> 1) ^ hx)) * 8 + (c4l & 1) * 4]);
        bf16x4 hi = *(const bf16x4*)(
            &sV[bb][(base + ((c4h >> 1) ^ hx)) * 8 + (c4h & 1) * 4]);
        bf16x8 vf = __builtin_shufflevector(lo, hi, 0, 1, 2, 3, 4, 5, 6, 7);
        oacc[0][ni] = MFMA(vf, pkv[0][c].v, oacc[0][ni]);
        oacc[1][ni] = MFMA(vf, pkv[1][c].v, oacc[1][ni]);
      }
    }
  }
  // epilogue: O^T C-layout -> O[b][t=q][h*128 + hd], 4 contiguous d per lane
#pragma unroll
  for (int g2 = 0; g2 < 2; g2++) {
    const float inv = 1.f / l_i[g2];
    unsigned short* Orow = O + (size_t)(b * kT + qA + 16 * g2) * kD + h * kHD;
#pragma unroll
    for (int ni = 0; ni < 8; ni++) {
      ushort4 o4;
      o4.x = f2bf(oacc[g2][ni][0] * inv);
      o4.y = f2bf(oacc[g2][ni][1] * inv);
      o4.z = f2bf(oacc[g2][ni][2] * inv);
      o4.w = f2bf(oacc[g2][ni][3] * inv);
      *(ushort4*)(Orow + ni * 16 + g * 4) = o4;
    }
  }
}

extern "C" void kernel_launch(void* const* d_in, const int* in_sizes, int n_in,
                              void* d_out, int out_size, void* d_ws, size_t ws_size,
                              hipStream_t stream) {
  const float* x       = (const float*)d_in[0];
  const float* Wq      = (const float*)d_in[1];
  const float* bq      = (const float*)d_in[2];
  const float* Wk      = (const float*)d_in[3];
  const float* bk      = (const float*)d_in[4];
  // d_in[5] Wvq, d_in[6] bvq, d_in[7] v_keys: dead (top_k selects all NVK)
  const float* v_embed = (const float*)d_in[8];
  const float* Wo      = (const float*)d_in[9];
  const float* bo      = (const float*)d_in[10];
  float* out = (float*)d_out;

  char* w = (char*)d_ws;
  unsigned short* xb  = (unsigned short*)w; w += (size_t)kBT * kD * 2;  // 16MB
  unsigned short* qb  = (unsigned short*)w; w += (size_t)kBT * kD * 2;
  unsigned short* kb  = (unsigned short*)w; w += (size_t)kBT * kD * 2;
  unsigned short* ob  = (unsigned short*)w; w += (size_t)kBT * kD * 2;
  unsigned short* vtb = (unsigned short*)w; w += (size_t)kBT * kD * 2;
  unsigned short* wqb = (unsigned short*)w; w += (size_t)kD * kD * 2;   // 8MB
  unsigned short* wkb = (unsigned short*)w; w += (size_t)kD * kD * 2;
  unsigned short* wob = (unsigned short*)w; w += (size_t)kD * kD * 2;

  // x read once: emits xb (bf16) + V^T; weights converted separately
  make_vt_kernel<<<dim3(kT / 64, kH, kB), 256, 0, stream>>>(x, v_embed, vtb, xb);
  cvt3_kernel<<<dim3(kD * kD / 1024, 3), 256, 0, stream>>>(
      Wq, Wk, Wo, wqb, wkb, wob, kD * kD / 4);

  // fold softmax scale (1/sqrt(HD) * log2(e), exp2 domain) into Q projection
  const float scaleQ = 0.08838834764831845f * 1.4426950408889634f;
  // fused Q+K projections: grid.z picks weights/bias/output
  gemm_bt<true, true><<<dim3(kD / 128, kBT / 128, 2), 256, 0, stream>>>(
      xb, wqb, wkb, bq, bk, qb, kb, scaleQ, 1.0f);

  attn3_kernel<<<dim3(512), 256, 0, stream>>>(qb, kb, vtb, ob);

  gemm_bt<false, false><<<dim3(kD / 128, kBT / 128, 1), 256, 0, stream>>>(
      ob, wob, nullptr, bo, nullptr, out, nullptr, 1.0f, 1.0f);
}

// Round 7
// 340.941 us; speedup vs baseline: 1.3515x; 1.3515x over previous
//
#include <hip/hip_runtime.h>
#include <hip/hip_bf16.h>

#define DEV __device__ __forceinline__

typedef __bf16 bf16x8 __attribute__((ext_vector_type(8)));
typedef __bf16 bf16x4 __attribute__((ext_vector_type(4)));
typedef float f32x4 __attribute__((ext_vector_type(4)));

static constexpr int kB = 2, kT = 2048, kD = 2048, kH = 16, kHD = 128;
static constexpr int kBT = kB * kT;  // 4096

#if __has_builtin(__builtin_amdgcn_exp2f)
DEV float fast_exp2(float x) { return __builtin_amdgcn_exp2f(x); }
#else
DEV float fast_exp2(float x) { return exp2f(x); }
#endif

DEV unsigned short f2bf(float f) {
  union { __hip_bfloat16 h; unsigned short u; } cv;
  cv.h = __float2bfloat16(f);
  return cv.u;
}

// async global->LDS, 16B per lane. LDS dest must be wave-uniform base + lane*16.
DEV void gl_lds16(const void* g, void* l) {
  __builtin_amdgcn_global_load_lds(
      (const __attribute__((address_space(1))) unsigned int*)g,
      (__attribute__((address_space(3))) unsigned int*)l, 16, 0, 0);
}

#define MFMA(a, b, c) __builtin_amdgcn_mfma_f32_16x16x32_bf16(a, b, c, 0, 0, 0)

// chunk swizzle for 128x64 bf16 tiles (8 chunks/row): frag-read lanes spread
// over all 8 4-bank spans (b128 floor). swz8 over 16 consecutive rows = 0..7 x2.
DEV int swz8(int row) { return (row ^ (row >> 3)) & 7; }

// ---------------- fp32 -> bf16 conversion of the 3 weight matrices ----------
__global__ __launch_bounds__(256) void cvt3_kernel(
    const float* __restrict__ s0, const float* __restrict__ s1,
    const float* __restrict__ s2, unsigned short* __restrict__ d0,
    unsigned short* __restrict__ d1, unsigned short* __restrict__ d2, int n4) {
  const int y = blockIdx.y;
  const float* s = y == 0 ? s0 : y == 1 ? s1 : s2;
  unsigned short* d = y == 0 ? d0 : y == 1 ? d1 : d2;
  int i = blockIdx.x * 256 + threadIdx.x;
  if (i >= n4) return;
  float4 v = ((const float4*)s)[i];
  ushort4 o;
  o.x = f2bf(v.x); o.y = f2bf(v.y); o.z = f2bf(v.z); o.w = f2bf(v.w);
  ((ushort4*)d)[i] = o;
}

// ---- make_vt + x-cvt fused: reads x once, emits xb (bf16) and V^T -----
// top_k with TOPK==NVK==4 selects ALL rows -> c[d] = 2*sum_{k<4} v_embed[k][d].
// Thread holds an 8t x 4d register block: xb written directly (coalesced);
// V^T transposed through 16B-chunk-swizzled LDS (b128 writes+reads, ~floor
// banks) then written coalesced to [b][h][hd][T].
__global__ __launch_bounds__(256) void make_vt_kernel(
    const float* __restrict__ x, const float* __restrict__ v_embed,
    unsigned short* __restrict__ vt, unsigned short* __restrict__ xb) {
  __shared__ __align__(16) unsigned short sT[128 * 64];  // [hd][chunk(t/8)][8]
  const int t0 = blockIdx.x * 64, h = blockIdx.y, b = blockIdx.z;
  const int tid = threadIdx.x;
  const int d4 = tid & 31, tw = tid >> 5;  // tw 0..7
  const int dg = h * kHD + d4 * 4;
  float4 e0 = *(const float4*)(v_embed + dg);
  float4 e1 = *(const float4*)(v_embed + kD + dg);
  float4 e2 = *(const float4*)(v_embed + 2 * kD + dg);
  float4 e3 = *(const float4*)(v_embed + 3 * kD + dg);
  float c4[4];
  c4[0] = 2.f * (e0.x + e1.x + e2.x + e3.x);
  c4[1] = 2.f * (e0.y + e1.y + e2.y + e3.y);
  c4[2] = 2.f * (e0.z + e1.z + e2.z + e3.z);
  c4[3] = 2.f * (e0.w + e1.w + e2.w + e3.w);
  float4 v[8];
#pragma unroll
  for (int j = 0; j < 8; j++)
    v[j] = *(const float4*)(x + (size_t)(b * kT + t0 + tw * 8 + j) * kD + dg);
  // xb: plain bf16 copy of x (coalesced 8B/lane)
#pragma unroll
  for (int j = 0; j < 8; j++) {
    ushort4 o;
    o.x = f2bf(v[j].x); o.y = f2bf(v[j].y); o.z = f2bf(v[j].z); o.w = f2bf(v[j].w);
    *(ushort4*)(xb + (size_t)(b * kT + t0 + tw * 8 + j) * kD + dg) = o;
  }
  // scaled transpose into LDS: row hd, chunk tw ^ (hd&7)
#pragma unroll
  for (int c = 0; c < 4; c++) {
    const int hd = d4 * 4 + c;
    union { bf16x8 v8; unsigned short u[8]; } w8;
#pragma unroll
    for (int j = 0; j < 8; j++)
      w8.u[j] = f2bf(((const float*)&v[j])[c] * c4[c]);
    *(bf16x8*)(&sT[hd * 64 + (tw ^ (hd & 7)) * 8]) = w8.v8;
  }
  __syncthreads();
#pragma unroll
  for (int it = 0; it < 4; it++) {
    const int hd = (tid >> 3) + it * 32;
    const int rc = tid & 7;
    bf16x8 vv = *(const bf16x8*)(&sT[hd * 64 + (rc ^ (hd & 7)) * 8]);
    *(bf16x8*)(vt + ((size_t)((b * kH + h) * kHD + hd)) * kT + t0 + rc * 8) = vv;
  }
}

// ---------------- C[m,n] = (sum_k A[m,k]*B[n,k] + bias[n]) * scale ----------
// 128x128 tile, BK=64 (32 iters, half the barriers vs BK=32), 4 waves (2x2),
// 16x16x32 MFMA, global_load_lds w=16, swz8 chunk swizzle.
// Staging: 128 rows x 8 chunks = 1024 lane-slots = 4 gl_lds16 calls per array.
template <bool BF16OUT, bool FUSED2>
__global__ __launch_bounds__(256, 4) void gemm_bt(
    const unsigned short* __restrict__ A, const unsigned short* __restrict__ B1,
    const unsigned short* __restrict__ B2, const float* __restrict__ bias1,
    const float* __restrict__ bias2, void* __restrict__ C1, void* __restrict__ C2,
    float scale1, float scale2) {
  constexpr int N = kD, K = kD;
  __shared__ __align__(16) unsigned short As[128 * 64], Bs[128 * 64];
  const unsigned short* Bm = (FUSED2 && blockIdx.z) ? B2 : B1;
  const float* bias = (FUSED2 && blockIdx.z) ? bias2 : bias1;
  void* Cout = (FUSED2 && blockIdx.z) ? C2 : C1;
  const float scale = (FUSED2 && blockIdx.z) ? scale2 : scale1;
  const int tid = threadIdx.x;
  const int lane = tid & 63, wave = tid >> 6;
  const int wr = wave >> 1, wc = wave & 1;
  const int m0 = blockIdx.y * 128, n0 = blockIdx.x * 128;
  const int frow = lane & 15, fc = lane >> 4;

  f32x4 acc[4][4];
  for (int i = 0; i < 4; i++)
    for (int j = 0; j < 4; j++)
      for (int r = 0; r < 4; r++) acc[i][j][r] = 0.f;

  const unsigned short* Ab = A + (size_t)m0 * K;
  const unsigned short* Bb = Bm + (size_t)n0 * K;

  for (int k0 = 0; k0 < K; k0 += 64) {
    __syncthreads();
#pragma unroll
    for (int i = 0; i < 4; i++) {  // 4 x 256 lanes = 1024 slots = 128 rows
      const int idx = tid + i * 256;
      const int row = idx >> 3, dc = (idx & 7) ^ swz8(row);
      gl_lds16(Ab + (size_t)row * K + k0 + dc * 8, As + idx * 8);
    }
#pragma unroll
    for (int i = 0; i < 4; i++) {
      const int idx = tid + i * 256;
      const int row = idx >> 3, dc = (idx & 7) ^ swz8(row);
      gl_lds16(Bb + (size_t)row * K + k0 + dc * 8, Bs + idx * 8);
    }
    __syncthreads();
#pragma unroll
    for (int ks = 0; ks < 2; ks++) {
      bf16x8 af[4], bfr[4];
#pragma unroll
      for (int mi = 0; mi < 4; mi++) {
        const int row = wr * 64 + mi * 16 + frow;
        af[mi] = *(const bf16x8*)(As + (row * 8 + ((ks * 4 + fc) ^ swz8(row))) * 8);
      }
#pragma unroll
      for (int ni = 0; ni < 4; ni++) {
        const int row = wc * 64 + ni * 16 + frow;
        bfr[ni] = *(const bf16x8*)(Bs + (row * 8 + ((ks * 4 + fc) ^ swz8(row))) * 8);
      }
#pragma unroll
      for (int mi = 0; mi < 4; mi++)
#pragma unroll
        for (int ni = 0; ni < 4; ni++)
          acc[mi][ni] = MFMA(af[mi], bfr[ni], acc[mi][ni]);
    }
  }
  // epilogue: C/D layout col=lane&15, row=(lane>>4)*4+reg
  for (int ni = 0; ni < 4; ni++) {
    const int n = n0 + wc * 64 + ni * 16 + frow;
    const float bs = bias[n];
    for (int mi = 0; mi < 4; mi++) {
      const int mb = m0 + wr * 64 + mi * 16 + fc * 4;
      for (int r = 0; r < 4; r++) {
        const float v = (acc[mi][ni][r] + bs) * scale;
        if (BF16OUT)
          ((unsigned short*)Cout)[(size_t)(mb + r) * N + n] = f2bf(v);
        else
          ((float*)Cout)[(size_t)(mb + r) * N + n] = v;
      }
    }
  }
}

// K/V tile staging: 64 keys x 128 hd each, 16B-chunk swizzled.
DEV void stage_kv(const unsigned short* __restrict__ Kg,
                  const unsigned short* __restrict__ Vt, unsigned short* dK,
                  unsigned short* dV, int tid, int b, int h, int k0) {
#pragma unroll
  for (int i = 0; i < 4; i++) {
    const int idx = tid + i * 256;
    const int key = idx >> 4, cc = (idx & 15) ^ (key & 15);
    gl_lds16(Kg + (size_t)(b * kT + k0 + key) * kD + h * kHD + cc * 8, dK + idx * 8);
  }
#pragma unroll
  for (int i = 0; i < 4; i++) {
    const int idx = tid + i * 256;
    const int hd = idx >> 3;
    const int cc = (idx & 7) ^ (hd & 7) ^ (((hd >> 3) & 1) << 2);
    gl_lds16(Vt + ((size_t)((b * kH + h) * kHD + hd)) * kT + k0 + cc * 8, dV + idx * 8);
  }
}

// ---------------- flash attention v3, causal, S^T formulation ----------------
// Q PRE-SCALED by (1/sqrt(HD))*log2(e); exp2-domain softmax. 128-row q-tile per
// block; each wave owns 32 q-columns (2 fragment groups) so every K/V LDS read
// feeds 2 MFMAs. Grid 512 (2 blocks/CU); adjacent bids pair qt=(15-j, j).
// PV via slot remap onto the K=32 MFMA (R4 notes).
__global__ __launch_bounds__(256, 2) void attn3_kernel(
    const unsigned short* __restrict__ Q, const unsigned short* __restrict__ Kg,
    const unsigned short* __restrict__ Vt, unsigned short* __restrict__ O) {
  __shared__ __align__(16) unsigned short sK[2][64 * 128];  // [key][hd]
  __shared__ __align__(16) unsigned short sV[2][64 * 128];  // [hd][key]
  const int tid = threadIdx.x, l = tid & 63, w = tid >> 6;
  const int g = l >> 4, q15 = l & 15;
  const int bid = blockIdx.x;
  const int pair = bid >> 1, j = pair >> 5;       // j 0..7
  const int qt = (bid & 1) ? j : (15 - j);        // heavy/light interleave
  const int gidx = pair & 31;
  const int h = gidx & 15, b = gidx >> 4;
  const int q0 = qt * 128;
  const int nkb = 2 * qt + 2;
  const int qA = q0 + w * 32 + q15;  // group 0 q; group 1 = qA+16

  stage_kv(Kg, Vt, &sK[0][0], &sV[0][0], tid, b, h, 0);

  bf16x8 qf[2][4];
#pragma unroll
  for (int g2 = 0; g2 < 2; g2++) {
    const unsigned short* Qrow = Q + (size_t)(b * kT + qA + 16 * g2) * kD + h * kHD;
#pragma unroll
    for (int kk = 0; kk < 4; kk++)
      qf[g2][kk] = *(const bf16x8*)(Qrow + kk * 32 + g * 8);
  }

  f32x4 oacc[2][8];
#pragma unroll
  for (int g2 = 0; g2 < 2; g2++)
    for (int ni = 0; ni < 8; ni++)
      for (int r = 0; r < 4; r++) oacc[g2][ni][r] = 0.f;
  float m_i[2] = {-1e30f, -1e30f}, l_i[2] = {0.f, 0.f};

  for (int kb = 0; kb < nkb; kb++) {
    const int bb = kb & 1;
    __syncthreads();  // drains prefetch(kb), syncs buffers
    if (kb + 1 < nkb)
      stage_kv(Kg, Vt, &sK[1 - bb][0], &sV[1 - bb][0], tid, b, h, (kb + 1) * 64);

    // S^T = K Q^T : lane holds S^T[key = s*16 + 4g + r][q(g2)]
    f32x4 st[2][4];
#pragma unroll
    for (int g2 = 0; g2 < 2; g2++)
      for (int s = 0; s < 4; s++)
        for (int r = 0; r < 4; r++) st[g2][s][r] = 0.f;
#pragma unroll
    for (int s = 0; s < 4; s++) {
      const int key = s * 16 + q15;  // A-frag row for this lane
#pragma unroll
      for (int kk = 0; kk < 4; kk++) {
        bf16x8 kf = *(const bf16x8*)(
            &sK[bb][(key * 16 + ((kk * 4 + g) ^ (key & 15))) * 8]);
        st[0][s] = MFMA(kf, qf[0][kk], st[0][s]);
        st[1][s] = MFMA(kf, qf[1][kk], st[1][s]);
      }
    }
    // causal mask (last two units hold the diagonal)
    if (kb >= nkb - 2) {
      const int kbase = kb * 64;
#pragma unroll
      for (int g2 = 0; g2 < 2; g2++)
        for (int s = 0; s < 4; s++)
          for (int r = 0; r < 4; r++)
            if (kbase + s * 16 + g * 4 + r > qA + 16 * g2) st[g2][s][r] = -1e30f;
    }
    // online softmax per group (exp2 domain), stats in-register + 2 shfl
    union { bf16x8 v; unsigned short u[8]; } pkv[2][2];
#pragma unroll
    for (int g2 = 0; g2 < 2; g2++) {
      float mx = -1e30f;
#pragma unroll
      for (int s = 0; s < 4; s++)
        for (int r = 0; r < 4; r++) mx = fmaxf(mx, st[g2][s][r]);
      mx = fmaxf(mx, __shfl_xor(mx, 16, 64));
      mx = fmaxf(mx, __shfl_xor(mx, 32, 64));
      const float mn = fmaxf(m_i[g2], mx);
      const float alpha = fast_exp2(m_i[g2] - mn);
      float rs = 0.f;
#pragma unroll
      for (int s = 0; s < 4; s++)
        for (int r = 0; r < 4; r++) {
          const float p = fast_exp2(st[g2][s][r] - mn);
          rs += p;
          pkv[g2][s >> 1].u[(s & 1) * 4 + r] = f2bf(p);  // slot j=(s&1)*4+r
        }
      rs += __shfl_xor(rs, 16, 64);
      rs += __shfl_xor(rs, 32, 64);
      m_i[g2] = mn;
      l_i[g2] = l_i[g2] * alpha + rs;
#pragma unroll
      for (int ni = 0; ni < 8; ni++)
        for (int r = 0; r < 4; r++) oacc[g2][ni][r] *= alpha;
    }
    // O^T += V^T P^T; A-frag slot (g,j) = key 32c+(j>>2)*16+4g+(j&3); V read
    // once, used by both groups.
#pragma unroll
    for (int ni = 0; ni < 8; ni++) {
      const int hd = ni * 16 + q15;
      const int hx = (hd & 7) ^ (((hd >> 3) & 1) << 2), base = hd * 8;
#pragma unroll
      for (int c = 0; c < 2; c++) {
        const int c4l = 8 * c + g;       // keys 32c+4g+0..3   (j=0..3)
        const int c4h = 8 * c + 4 + g;   // keys 32c+16+4g+0..3 (j=4..7)
        bf16x4 lo = *(const bf16x4*)(
            &sV[bb][(base + ((c4l >> 1) ^ hx)) * 8 + (c4l & 1) * 4]);
        bf16x4 hi = *(const bf16x4*)(
            &sV[bb][(base + ((c4h >> 1) ^ hx)) * 8 + (c4h & 1) * 4]);
        bf16x8 vf = __builtin_shufflevector(lo, hi, 0, 1, 2, 3, 4, 5, 6, 7);
        oacc[0][ni] = MFMA(vf, pkv[0][c].v, oacc[0][ni]);
        oacc[1][ni] = MFMA(vf, pkv[1][c].v, oacc[1][ni]);
      }
    }
  }
  // epilogue: O^T C-layout -> O[b][t=q][h*128 + hd], 4 contiguous d per lane
#pragma unroll
  for (int g2 = 0; g2 < 2; g2++) {
    const float inv = 1.f / l_i[g2];
    unsigned short* Orow = O + (size_t)(b * kT + qA + 16 * g2) * kD + h * kHD;
#pragma unroll
    for (int ni = 0; ni < 8; ni++) {
      ushort4 o4;
      o4.x = f2bf(oacc[g2][ni][0] * inv);
      o4.y = f2bf(oacc[g2][ni][1] * inv);
      o4.z = f2bf(oacc[g2][ni][2] * inv);
      o4.w = f2bf(oacc[g2][ni][3] * inv);
      *(ushort4*)(Orow + ni * 16 + g * 4) = o4;
    }
  }
}

extern "C" void kernel_launch(void* const* d_in, const int* in_sizes, int n_in,
                              void* d_out, int out_size, void* d_ws, size_t ws_size,
                              hipStream_t stream) {
  const float* x       = (const float*)d_in[0];
  const float* Wq      = (const float*)d_in[1];
  const float* bq      = (const float*)d_in[2];
  const float* Wk      = (const float*)d_in[3];
  const float* bk      = (const float*)d_in[4];
  // d_in[5] Wvq, d_in[6] bvq, d_in[7] v_keys: dead (top_k selects all NVK)
  const float* v_embed = (const float*)d_in[8];
  const float* Wo      = (const float*)d_in[9];
  const float* bo      = (const float*)d_in[10];
  float* out = (float*)d_out;

  char* w = (char*)d_ws;
  unsigned short* xb  = (unsigned short*)w; w += (size_t)kBT * kD * 2;  // 16MB
  unsigned short* qb  = (unsigned short*)w; w += (size_t)kBT * kD * 2;
  unsigned short* kb  = (unsigned short*)w; w += (size_t)kBT * kD * 2;
  unsigned short* ob  = (unsigned short*)w; w += (size_t)kBT * kD * 2;
  unsigned short* vtb = (unsigned short*)w; w += (size_t)kBT * kD * 2;
  unsigned short* wqb = (unsigned short*)w; w += (size_t)kD * kD * 2;   // 8MB
  unsigned short* wkb = (unsigned short*)w; w += (size_t)kD * kD * 2;
  unsigned short* wob = (unsigned short*)w; w += (size_t)kD * kD * 2;

  // x read once: emits xb (bf16) + V^T; weights converted separately
  make_vt_kernel<<<dim3(kT / 64, kH, kB), 256, 0, stream>>>(x, v_embed, vtb, xb);
  cvt3_kernel<<<dim3(kD * kD / 1024, 3), 256, 0, stream>>>(
      Wq, Wk, Wo, wqb, wkb, wob, kD * kD / 4);

  // fold softmax scale (1/sqrt(HD) * log2(e), exp2 domain) into Q projection
  const float scaleQ = 0.08838834764831845f * 1.4426950408889634f;
  // fused Q+K projections: grid.z picks weights/bias/output
  gemm_bt<true, true><<<dim3(kD / 128, kBT / 128, 2), 256, 0, stream>>>(
      xb, wqb, wkb, bq, bk, qb, kb, scaleQ, 1.0f);

  attn3_kernel<<<dim3(512), 256, 0, stream>>>(qb, kb, vtb, ob);

  gemm_bt<false, false><<<dim3(kD / 128, kBT / 128, 1), 256, 0, stream>>>(
      ob, wob, nullptr, bo, nullptr, out, nullptr, 1.0f, 1.0f);
}